// Round 11
// baseline (645.726 us; speedup 1.0000x reference)
//
#include <hip/hip_runtime.h>

#define N_NODES 100000
#define E_EDGES 800000
#define E_TOT   900000
#define F 512

typedef __attribute__((ext_vector_type(8))) short short8;
typedef __attribute__((ext_vector_type(4))) float f32x4;
typedef unsigned int u32;

__device__ __forceinline__ float bfu(unsigned int u) {
    union { unsigned int i; float f; } c; c.i = u << 16; return c.f;
}
__device__ __forceinline__ unsigned short f2b(float f) {
    union { float f; unsigned int u; } c; c.f = f;
    return (unsigned short)((c.u + 0x7fffu + ((c.u >> 16) & 1u)) >> 16);
}
__device__ __forceinline__ float fbits(unsigned int u) {
    union { unsigned int i; float f; } c; c.i = u; return c.f;
}
__device__ __forceinline__ unsigned int bits(float f) {
    union { float f; unsigned int i; } c; c.f = f; return c.i;
}
__device__ __forceinline__ void gload_lds16(const void* g, void* l) {
    __builtin_amdgcn_global_load_lds(
        (const __attribute__((address_space(1))) u32*)g,
        (__attribute__((address_space(3))) u32*)l, 16, 0, 0);
}

// ---- CSR build ----
__global__ void k_init(unsigned int* deg, unsigned int* counter) {
    int i = blockIdx.x * 256 + threadIdx.x;
    if (i < N_NODES) deg[i] = 1u;           // self loop
    if (i == 0) *counter = 0u;
}

__global__ void k_hist(const int* __restrict__ ei, unsigned int* deg) {
    int e = blockIdx.x * 256 + threadIdx.x;
    if (e < E_EDGES) atomicAdd(&deg[ei[E_EDGES + e]], 1u);
}

__global__ void k_disalloc(const unsigned int* __restrict__ deg, unsigned int* counter,
                           float* __restrict__ dis,
                           int2* __restrict__ seg, unsigned int* __restrict__ cursor) {
    int i = blockIdx.x * 256 + threadIdx.x;
    if (i < N_NODES) {
        unsigned int d = deg[i];
        dis[i] = rsqrtf((float)d);
        unsigned int p = atomicAdd(counter, d);
        seg[i] = make_int2((int)p, (int)(p + d));
        cursor[i] = p;
    }
}

__global__ void k_scatter(const int* __restrict__ ei, const float* __restrict__ dis,
                          unsigned int* __restrict__ cursor,
                          uint2* __restrict__ ev) {
    int e = blockIdx.x * 256 + threadIdx.x;
    if (e < E_TOT) {
        int s, d;
        if (e < E_EDGES) { s = ei[e]; d = ei[E_EDGES + e]; }
        else             { s = e - E_EDGES; d = s; }
        unsigned int p = atomicAdd(&cursor[d], 1u);
        ev[p] = make_uint2((unsigned)s, bits(dis[s] * dis[d]));
    }
}

// ---- dtype converts ----
__global__ void k_cvtX(const float* __restrict__ xin, unsigned short* __restrict__ xb) {
    int i = blockIdx.x * 256 + threadIdx.x;
    const f32x4* p = (const f32x4*)xin + (size_t)i * 2;
    f32x4 a = __builtin_nontemporal_load(p);
    f32x4 b = __builtin_nontemporal_load(p + 1);
    uint4 o;
    o.x = (unsigned)f2b(a[0]) | ((unsigned)f2b(a[1]) << 16);
    o.y = (unsigned)f2b(a[2]) | ((unsigned)f2b(a[3]) << 16);
    o.z = (unsigned)f2b(b[0]) | ((unsigned)f2b(b[1]) << 16);
    o.w = (unsigned)f2b(b[2]) | ((unsigned)f2b(b[3]) << 16);
    *(uint4*)(xb + (size_t)i * 8) = o;
}

__global__ void k_cvtW(const float* __restrict__ W1, const float* __restrict__ W2,
                       unsigned short* __restrict__ W1t, unsigned short* __restrict__ W2t) {
    int t = blockIdx.x * 256 + threadIdx.x;
    int which = t >= F * F;
    int u = t - which * F * F;
    int n = u >> 9, k = u & 511;
    const float* W = which ? W2 : W1;
    unsigned short* Wt = which ? W2t : W1t;
    Wt[u] = f2b(W[k * F + n]);
}

// ---- GEMM 256x256, 8-phase counted-vmcnt schedule (T2+T3+T4+T5) ----
// 512 threads = 8 waves (2M x 4N), BK=64, LDS 128 KB dbuf, XOR-swizzled.
// Per K-tile: 4 phases (quadrant ks=i>>1, mh=i&1). Phase 0 stages chunks 0+1
// of tile t+1 and waits vmcnt(4) (all of tile t retired, only the 4 new
// loads outstanding); phase 1 stages chunks 2+3; phases 2-3 stage nothing.
// Last tile: vmcnt(0) at phase 0. Never drains mid-loop.

#define STAGE_CHUNK(BUF, I, K0) { \
    gload_lds16(A + (size_t)ar[I] * F + (K0) + kcs[I], sm + (BUF) * 16384 + ((I) * 512 + t) * 8); \
    gload_lds16(Bt + (size_t)br[I] * F + (K0) + kcs[I], sm + 32768 + (BUF) * 16384 + ((I) * 512 + t) * 8); }

#define PHASE(BUF, I, WLIT, DOWAIT, DOSTAGE, K0N) { \
    if (DOSTAGE) { \
        STAGE_CHUNK((BUF) ^ 1, 2 * (I), K0N) \
        STAGE_CHUNK((BUF) ^ 1, 2 * (I) + 1, K0N) \
    } \
    if (DOWAIT) { asm volatile("s_waitcnt vmcnt(" #WLIT ")" ::: "memory"); } \
    __builtin_amdgcn_s_barrier(); \
    asm volatile("" ::: "memory"); \
    { \
        const unsigned short* la = sm + (BUF) * 16384; \
        const unsigned short* lb = sm + 32768 + (BUF) * 16384; \
        const int ksq = (I) >> 1, mhq = (I) & 1; \
        int koff = (ksq * 32 + khalf) ^ kx; \
        short8 af_[4]; \
        _Pragma("unroll") \
        for (int m4 = 0; m4 < 4; ++m4) \
            af_[m4] = *(const short8*)&la[(wr * 128 + (mhq * 4 + m4) * 16 + rsel) * 64 + koff]; \
        if (mhq == 0) { \
            _Pragma("unroll") \
            for (int n = 0; n < 4; ++n) \
                bfr[n] = *(const short8*)&lb[(wc * 64 + n * 16 + rsel) * 64 + koff]; \
        } \
        __builtin_amdgcn_s_setprio(1); \
        _Pragma("unroll") \
        for (int m4 = 0; m4 < 4; ++m4) \
            _Pragma("unroll") \
            for (int n = 0; n < 4; ++n) \
                acc[mhq * 4 + m4][n] = __builtin_amdgcn_mfma_f32_16x16x32_bf16(af_[m4], bfr[n], acc[mhq * 4 + m4][n], 0, 0, 0); \
        __builtin_amdgcn_s_setprio(0); \
    } \
    __builtin_amdgcn_s_barrier(); }

// one K-tile with prefetch of tile at K0N
#define KTILE(BUF, K0N) \
    PHASE(BUF, 0, 4, 1, 1, K0N) PHASE(BUF, 1, 8, 0, 1, K0N) \
    PHASE(BUF, 2, 8, 0, 0, 0)   PHASE(BUF, 3, 8, 0, 0, 0)

__global__ __launch_bounds__(512, 2)
void gemm_bt(const unsigned short* __restrict__ A, const unsigned short* __restrict__ Bt,
             const float* __restrict__ bias,
             unsigned short* __restrict__ outb, float* __restrict__ outf,
             int relu, int M) {
    __shared__ unsigned short sm[65536];          // 128 KB
    // shorts: A buf0 @0, A buf1 @16384, B buf0 @32768, B buf1 @49152

    // bijective XCD remap (m204)
    int nwg = gridDim.x * gridDim.y;
    int orig = blockIdx.y * gridDim.x + blockIdx.x;
    int q = nwg >> 3, r = nwg & 7;
    int xcd = orig & 7, j8 = orig >> 3;
    int wgid = (xcd < r ? xcd * (q + 1) : r * (q + 1) + (xcd - r) * q) + j8;
    int by = wgid & 1;
    int bx = wgid >> 1;

    int t  = threadIdx.x;
    int lane = t & 63, w = t >> 6;
    int wr = w >> 2, wc = w & 3;
    int rsel = lane & 15, khalf = (lane >> 4) * 8;
    int kx = (lane & 4) ? 16 : 0;                 // read-side swizzle XOR (shorts)

    f32x4 acc[8][4];
    #pragma unroll
    for (int m = 0; m < 8; ++m)
        #pragma unroll
        for (int n = 0; n < 4; ++n)
            acc[m][n] = (f32x4){0.f, 0.f, 0.f, 0.f};

    int rowBase = bx * 256;

    // staging coords: chunk i, idx=i*512+t: row=idx>>3, colbase=(idx&7)*8;
    // source pre-swizzle: col ^16 shorts when row&4 (involution; LDS dest linear)
    int ar[4], br[4], kcs[4];
    #pragma unroll
    for (int i = 0; i < 4; ++i) {
        int idx = i * 512 + t;
        int rr = idx >> 3;
        int kc = (idx & 7) * 8;
        kcs[i] = kc ^ ((rr & 4) ? 16 : 0);
        int ga = rowBase + rr; if (ga >= M) ga = M - 1;
        ar[i] = ga;
        br[i] = by * 256 + rr;
    }

    short8 bfr[4];

    // prologue: stage tile 0 (8 loads) into buf0
    STAGE_CHUNK(0, 0, 0) STAGE_CHUNK(0, 1, 0) STAGE_CHUNK(0, 2, 0) STAGE_CHUNK(0, 3, 0)

    // K = 512 = 8 tiles of 64; tile t in buf(t&1); tiles 0..6 prefetch t+1
    KTILE(0,  64) KTILE(1, 128) KTILE(0, 192) KTILE(1, 256)
    KTILE(0, 320) KTILE(1, 384) KTILE(0, 448)
    // last tile: drain (vmcnt 0 at phase 0), no staging
    PHASE(1, 0, 0, 1, 0, 0) PHASE(1, 1, 0, 0, 0, 0)
    PHASE(1, 2, 0, 0, 0, 0) PHASE(1, 3, 0, 0, 0, 0)

    int rq = (lane >> 4) * 4, cq = lane & 15;
    if (outb) {
        // stage bf16 C-tile in LDS, then coalesced 512B-row stores
        #pragma unroll
        for (int m = 0; m < 8; ++m)
            #pragma unroll
            for (int n = 0; n < 4; ++n) {
                int cl = wc * 64 + n * 16 + cq;
                float bv = bias[by * 256 + cl];
                #pragma unroll
                for (int j = 0; j < 4; ++j) {
                    int rl = wr * 128 + m * 16 + rq + j;
                    float v = acc[m][n][j] + bv;
                    if (relu) v = fmaxf(v, 0.f);
                    sm[rl * 256 + cl] = f2b(v);
                }
            }
        __syncthreads();
        #pragma unroll
        for (int p = 0; p < 16; ++p) {
            int sidx = p * 4096 + t * 8;
            int row = sidx >> 8;
            int col = sidx & 255;
            int grow = rowBase + row;
            if (grow < M) {
                uint4 v = *(const uint4*)&sm[sidx];
                *(uint4*)&outb[(size_t)grow * F + by * 256 + col] = v;
            }
        }
    } else {
        #pragma unroll
        for (int m = 0; m < 8; ++m)
            #pragma unroll
            for (int n = 0; n < 4; ++n) {
                int colv = by * 256 + wc * 64 + n * 16 + cq;
                float bv = bias[colv];
                #pragma unroll
                for (int j = 0; j < 4; ++j) {
                    int row = rowBase + wr * 128 + m * 16 + rq + j;
                    if (row < M) {
                        float v = acc[m][n][j] + bv;
                        if (relu) v = fmaxf(v, 0.f);
                        __builtin_nontemporal_store(v, outf + (size_t)row * F + colv);
                    }
                }
            }
    }
}

// ---- aggregation: g[d] = sum_e val[e] * hin[col[e]]  (512-wide, x8 unroll) ----
#define LOADP(k) uint2 p##k = ev[e + k]
#define LOADV(k) uint4 v##k = *(const uint4*)(base + ((size_t)p##k.x << 9))
#define ACCV(k)  { float w_ = fbits(p##k.y); \
    acc[0] += w_ * bfu(v##k.x & 0xffffu); acc[1] += w_ * bfu(v##k.x >> 16); \
    acc[2] += w_ * bfu(v##k.y & 0xffffu); acc[3] += w_ * bfu(v##k.y >> 16); \
    acc[4] += w_ * bfu(v##k.z & 0xffffu); acc[5] += w_ * bfu(v##k.z >> 16); \
    acc[6] += w_ * bfu(v##k.w & 0xffffu); acc[7] += w_ * bfu(v##k.w >> 16); }

__global__ __launch_bounds__(256)
void k_agg(const unsigned short* __restrict__ hin, const int2* __restrict__ seg,
           const uint2* __restrict__ ev,
           unsigned short* __restrict__ outb) {
    int node = blockIdx.x * 4 + (threadIdx.x >> 6);
    int lane = threadIdx.x & 63;
    if (node >= N_NODES) return;
    int2 se = seg[node];
    int e0 = se.x, e1 = se.y;
    float acc[8] = {0, 0, 0, 0, 0, 0, 0, 0};
    const unsigned short* base = hin + lane * 8;

    int e = e0;
    int n8 = e0 + ((e1 - e0) & ~7);
    for (; e < n8; e += 8) {
        LOADP(0); LOADP(1); LOADP(2); LOADP(3);
        LOADP(4); LOADP(5); LOADP(6); LOADP(7);
        LOADV(0); LOADV(1); LOADV(2); LOADV(3);
        LOADV(4); LOADV(5); LOADV(6); LOADV(7);
        ACCV(0); ACCV(1); ACCV(2); ACCV(3);
        ACCV(4); ACCV(5); ACCV(6); ACCV(7);
    }
    for (; e < e1; ++e) {
        LOADP(0); LOADV(0); ACCV(0);
    }

    uint4 o;
    o.x = (unsigned)f2b(acc[0]) | ((unsigned)f2b(acc[1]) << 16);
    o.y = (unsigned)f2b(acc[2]) | ((unsigned)f2b(acc[3]) << 16);
    o.z = (unsigned)f2b(acc[4]) | ((unsigned)f2b(acc[5]) << 16);
    o.w = (unsigned)f2b(acc[6]) | ((unsigned)f2b(acc[7]) << 16);
    *(uint4*)(outb + (size_t)node * F + lane * 8) = o;
}

extern "C" void kernel_launch(void* const* d_in, const int* in_sizes, int n_in,
                              void* d_out, int out_size, void* d_ws, size_t ws_size,
                              hipStream_t stream) {
    const float* x  = (const float*)d_in[0];
    const int*   ei = (const int*)d_in[1];
    const float* W1 = (const float*)d_in[2];
    const float* b1 = (const float*)d_in[3];
    const float* W2 = (const float*)d_in[4];
    const float* b2 = (const float*)d_in[5];
    float* out = (float*)d_out;

    char* ws = (char*)d_ws;
    size_t off = 0;
    auto alloc = [&](size_t bytes) -> void* {
        off = (off + 255) & ~(size_t)255;
        void* p = ws + off;
        off += bytes;
        return p;
    };

    unsigned short* tb  = (unsigned short*)alloc((size_t)N_NODES * F * 2); // agg out (bf16)
    unsigned short* W1t = (unsigned short*)alloc((size_t)F * F * 2);
    unsigned short* W2t = (unsigned short*)alloc((size_t)F * F * 2);
    unsigned int*   deg = (unsigned int*)alloc((size_t)N_NODES * 4);
    float*          dis = (float*)alloc((size_t)N_NODES * 4);
    int2*           seg = (int2*)alloc((size_t)N_NODES * 8);
    unsigned int*   cur = (unsigned int*)alloc((size_t)N_NODES * 4);
    unsigned int*   cnt = (unsigned int*)alloc(256);
    uint2*          ev  = (uint2*)alloc((size_t)E_TOT * 8);

    // d_out doubles as scratch: lower half = h1 (bf16), upper half = x (bf16).
    unsigned short* h1b = (unsigned short*)d_out;
    unsigned short* xb  = (unsigned short*)((char*)d_out + (size_t)N_NODES * F * 2);

    int nb = (N_NODES + 255) / 256;

    k_init<<<nb, 256, 0, stream>>>(deg, cnt);
    k_hist<<<(E_EDGES + 255) / 256, 256, 0, stream>>>(ei, deg);
    k_disalloc<<<nb, 256, 0, stream>>>(deg, cnt, dis, seg, cur);
    k_scatter<<<(E_TOT + 255) / 256, 256, 0, stream>>>(ei, dis, cur, ev);

    k_cvtW<<<(2 * F * F) / 256, 256, 0, stream>>>(W1, W2, W1t, W2t);
    k_cvtX<<<(N_NODES * F / 8) / 256, 256, 0, stream>>>(x, xb);

    dim3 ggrid(2, (N_NODES + 255) / 256);

    // layer 1: h1 = relu((A x) W1 + b1)   [reassociated]
    k_agg<<<(N_NODES + 3) / 4, 256, 0, stream>>>(xb, seg, ev, tb);
    gemm_bt<<<ggrid, 512, 0, stream>>>(tb, W1t, b1, h1b, nullptr, 1, N_NODES);

    // layer 2: out = (A h1) W2 + b2       [reassociated]
    k_agg<<<(N_NODES + 3) / 4, 256, 0, stream>>>(h1b, seg, ev, tb);
    gemm_bt<<<ggrid, 512, 0, stream>>>(tb, W2t, b2, nullptr, out, 0, N_NODES);
}

// Round 13
// 617.901 us; speedup vs baseline: 1.0450x; 1.0450x over previous
//
#include <hip/hip_runtime.h>

#define N_NODES 100000
#define E_EDGES 800000
#define E_TOT   900000
#define F 512

typedef __attribute__((ext_vector_type(8))) short short8;
typedef __attribute__((ext_vector_type(4))) float f32x4;
typedef unsigned int u32;

__device__ __forceinline__ float bfu(unsigned int u) {
    union { unsigned int i; float f; } c; c.i = u << 16; return c.f;
}
__device__ __forceinline__ unsigned short f2b(float f) {
    union { float f; unsigned int u; } c; c.f = f;
    return (unsigned short)((c.u + 0x7fffu + ((c.u >> 16) & 1u)) >> 16);
}
__device__ __forceinline__ float fbits(unsigned int u) {
    union { unsigned int i; float f; } c; c.i = u; return c.f;
}
__device__ __forceinline__ unsigned int bits(float f) {
    union { float f; unsigned int i; } c; c.f = f; return c.i;
}
__device__ __forceinline__ void gload_lds16(const void* g, void* l) {
    __builtin_amdgcn_global_load_lds(
        (const __attribute__((address_space(1))) u32*)g,
        (__attribute__((address_space(3))) u32*)l, 16, 0, 0);
}

// ---- CSR build ----
__global__ void k_init(unsigned int* deg, unsigned int* counter) {
    int i = blockIdx.x * 256 + threadIdx.x;
    if (i < N_NODES) deg[i] = 1u;           // self loop
    if (i == 0) *counter = 0u;
}

__global__ void k_hist(const int* __restrict__ ei, unsigned int* deg) {
    int e = blockIdx.x * 256 + threadIdx.x;
    if (e < E_EDGES) atomicAdd(&deg[ei[E_EDGES + e]], 1u);
}

__global__ void k_disalloc(const unsigned int* __restrict__ deg, unsigned int* counter,
                           float* __restrict__ dis,
                           int2* __restrict__ seg, unsigned int* __restrict__ cursor) {
    int i = blockIdx.x * 256 + threadIdx.x;
    if (i < N_NODES) {
        unsigned int d = deg[i];
        dis[i] = rsqrtf((float)d);
        unsigned int p = atomicAdd(counter, d);
        seg[i] = make_int2((int)p, (int)(p + d));
        cursor[i] = p;
    }
}

__global__ void k_scatter(const int* __restrict__ ei, const float* __restrict__ dis,
                          unsigned int* __restrict__ cursor,
                          uint2* __restrict__ ev) {
    int e = blockIdx.x * 256 + threadIdx.x;
    if (e < E_TOT) {
        int s, d;
        if (e < E_EDGES) { s = ei[e]; d = ei[E_EDGES + e]; }
        else             { s = e - E_EDGES; d = s; }
        unsigned int p = atomicAdd(&cursor[d], 1u);
        ev[p] = make_uint2((unsigned)s, bits(dis[s] * dis[d]));
    }
}

// ---- dtype converts ----
__global__ void k_cvtX(const float* __restrict__ xin, unsigned short* __restrict__ xb) {
    int i = blockIdx.x * 256 + threadIdx.x;
    const f32x4* p = (const f32x4*)xin + (size_t)i * 2;
    f32x4 a = __builtin_nontemporal_load(p);
    f32x4 b = __builtin_nontemporal_load(p + 1);
    uint4 o;
    o.x = (unsigned)f2b(a[0]) | ((unsigned)f2b(a[1]) << 16);
    o.y = (unsigned)f2b(a[2]) | ((unsigned)f2b(a[3]) << 16);
    o.z = (unsigned)f2b(b[0]) | ((unsigned)f2b(b[1]) << 16);
    o.w = (unsigned)f2b(b[2]) | ((unsigned)f2b(b[3]) << 16);
    *(uint4*)(xb + (size_t)i * 8) = o;
}

__global__ void k_cvtW(const float* __restrict__ W1, const float* __restrict__ W2,
                       unsigned short* __restrict__ W1t, unsigned short* __restrict__ W2t) {
    int t = blockIdx.x * 256 + threadIdx.x;
    int which = t >= F * F;
    int u = t - which * F * F;
    int n = u >> 9, k = u & 511;
    const float* W = which ? W2 : W1;
    unsigned short* Wt = which ? W2t : W1t;
    Wt[u] = f2b(W[k * F + n]);
}

// ---- GEMM 256x128, BK=32, 2-phase dbuf, 48 KB LDS -> 2 blocks/CU ----
// 512 threads = 8 waves (4M x 2N); per-wave 64x64 out (acc[4][4], ~115 VGPR).
// Mechanism: co-resident block covers this block's staging stalls (m114).
__global__ __launch_bounds__(512, 4)
void gemm_bt(const unsigned short* __restrict__ A, const unsigned short* __restrict__ Bt,
             const float* __restrict__ bias,
             unsigned short* __restrict__ outb, float* __restrict__ outf,
             int relu, int M) {
    __shared__ unsigned short sm[24576];  // 48 KB: A0@0, A1@8192, B0@16384, B1@20480

    // bijective XCD remap: 4 N-siblings of one A-slab -> same XCD, adjacent
    int nwg = gridDim.x * gridDim.y;              // 1564
    int orig = blockIdx.y * gridDim.x + blockIdx.x;
    int q = nwg >> 3, r = nwg & 7;
    int xcd = orig & 7, j8 = orig >> 3;
    int wgid = (xcd < r ? xcd * (q + 1) : r * (q + 1) + (xcd - r) * q) + j8;
    int by = wgid & 3;                            // N tile (0..3), 128 cols
    int bx = wgid >> 2;                           // M tile (0..390)

    int t  = threadIdx.x;
    int lane = t & 63, w = t >> 6;
    int wr = w >> 1, wc = w & 1;
    int rsel = lane & 15, khalf = (lane >> 4) * 8;

    f32x4 acc[4][4];
    #pragma unroll
    for (int m = 0; m < 4; ++m)
        #pragma unroll
        for (int n = 0; n < 4; ++n)
            acc[m][n] = (f32x4){0.f, 0.f, 0.f, 0.f};

    int rowBase = bx * 256;

    // A staging: 1024 16B-chunks (2/thread); chunk idx: row=idx>>2, kc=(idx&3)*8
    int arA[2], kcA[2];
    #pragma unroll
    for (int i = 0; i < 2; ++i) {
        int idx = i * 512 + t;
        int rr = idx >> 2;
        kcA[i] = (idx & 3) * 8;
        int ga = rowBase + rr; if (ga >= M) ga = M - 1;
        arA[i] = ga;
    }
    // B staging: 512 chunks (1/thread)
    int brB = by * 128 + (t >> 2);
    int kcB = (t & 3) * 8;

    auto STAGE = [&](int buf, int k0) {
        gload_lds16(A + (size_t)arA[0] * F + k0 + kcA[0], sm + buf * 8192 + t * 8);
        gload_lds16(A + (size_t)arA[1] * F + k0 + kcA[1], sm + buf * 8192 + (512 + t) * 8);
        gload_lds16(Bt + (size_t)brB * F + k0 + kcB, sm + 16384 + buf * 4096 + t * 8);
    };
    auto COMPUTE = [&](int buf) {
        const unsigned short* la = sm + buf * 8192;
        const unsigned short* lb = sm + 16384 + buf * 4096;
        short8 bfr[4];
        #pragma unroll
        for (int n = 0; n < 4; ++n)
            bfr[n] = *(const short8*)&lb[(wc * 64 + n * 16 + rsel) * 32 + khalf];
        #pragma unroll
        for (int m = 0; m < 4; ++m) {
            short8 af = *(const short8*)&la[(wr * 64 + m * 16 + rsel) * 32 + khalf];
            #pragma unroll
            for (int n = 0; n < 4; ++n)
                acc[m][n] = __builtin_amdgcn_mfma_f32_16x16x32_bf16(af, bfr[n], acc[m][n], 0, 0, 0);
        }
    };

    // K = 512 = 16 tiles of 32; even tiles buf0, odd buf1
    STAGE(0, 0);
    __syncthreads();
    #pragma unroll
    for (int kp = 0; kp < 8; ++kp) {
        STAGE(1, (2 * kp + 1) * 32);
        COMPUTE(0);
        __syncthreads();
        if (kp < 7) STAGE(0, (2 * kp + 2) * 32);
        COMPUTE(1);
        __syncthreads();
    }

    int rq = (lane >> 4) * 4, cq = lane & 15;
    if (outb) {
        // restage bf16 C-tile through LDS in two 128x128 halves (32 KB each)
        #pragma unroll
        for (int h = 0; h < 2; ++h) {
            if (h) __syncthreads();               // previous copy-out done
            if ((wr >> 1) == h) {
                #pragma unroll
                for (int m = 0; m < 4; ++m)
                    #pragma unroll
                    for (int n = 0; n < 4; ++n) {
                        int cl = wc * 64 + n * 16 + cq;
                        float bv = bias[by * 128 + cl];
                        #pragma unroll
                        for (int j = 0; j < 4; ++j) {
                            int rl = (wr & 1) * 64 + m * 16 + rq + j;
                            float v = acc[m][n][j] + bv;
                            if (relu) v = fmaxf(v, 0.f);
                            sm[rl * 128 + cl] = f2b(v);
                        }
                    }
            }
            __syncthreads();
            // 128x128 half = 16384 shorts = 512 threads x 4 x 8
            #pragma unroll
            for (int p = 0; p < 4; ++p) {
                int sidx = (p * 512 + t) * 8;
                int row = sidx >> 7;
                int col = sidx & 127;
                int grow = rowBase + h * 128 + row;
                if (grow < M) {
                    uint4 v = *(const uint4*)&sm[sidx];
                    *(uint4*)&outb[(size_t)grow * F + by * 128 + col] = v;
                }
            }
        }
    } else {
        #pragma unroll
        for (int m = 0; m < 4; ++m)
            #pragma unroll
            for (int n = 0; n < 4; ++n) {
                int colv = by * 128 + wc * 64 + n * 16 + cq;
                float bv = bias[colv];
                #pragma unroll
                for (int j = 0; j < 4; ++j) {
                    int row = rowBase + wr * 64 + m * 16 + rq + j;
                    if (row < M) {
                        float v = acc[m][n][j] + bv;
                        if (relu) v = fmaxf(v, 0.f);
                        __builtin_nontemporal_store(v, outf + (size_t)row * F + colv);
                    }
                }
            }
    }
}

// ---- aggregation: g[d] = sum_e val[e] * hin[col[e]]  (512-wide, x8 unroll) ----
#define LOADP(k) uint2 p##k = ev[e + k]
#define LOADV(k) uint4 v##k = *(const uint4*)(base + ((size_t)p##k.x << 9))
#define ACCV(k)  { float w_ = fbits(p##k.y); \
    acc[0] += w_ * bfu(v##k.x & 0xffffu); acc[1] += w_ * bfu(v##k.x >> 16); \
    acc[2] += w_ * bfu(v##k.y & 0xffffu); acc[3] += w_ * bfu(v##k.y >> 16); \
    acc[4] += w_ * bfu(v##k.z & 0xffffu); acc[5] += w_ * bfu(v##k.z >> 16); \
    acc[6] += w_ * bfu(v##k.w & 0xffffu); acc[7] += w_ * bfu(v##k.w >> 16); }

__global__ __launch_bounds__(256)
void k_agg(const unsigned short* __restrict__ hin, const int2* __restrict__ seg,
           const uint2* __restrict__ ev,
           unsigned short* __restrict__ outb) {
    int node = blockIdx.x * 4 + (threadIdx.x >> 6);
    int lane = threadIdx.x & 63;
    if (node >= N_NODES) return;
    int2 se = seg[node];
    int e0 = se.x, e1 = se.y;
    float acc[8] = {0, 0, 0, 0, 0, 0, 0, 0};
    const unsigned short* base = hin + lane * 8;

    int e = e0;
    int n8 = e0 + ((e1 - e0) & ~7);
    for (; e < n8; e += 8) {
        LOADP(0); LOADP(1); LOADP(2); LOADP(3);
        LOADP(4); LOADP(5); LOADP(6); LOADP(7);
        LOADV(0); LOADV(1); LOADV(2); LOADV(3);
        LOADV(4); LOADV(5); LOADV(6); LOADV(7);
        ACCV(0); ACCV(1); ACCV(2); ACCV(3);
        ACCV(4); ACCV(5); ACCV(6); ACCV(7);
    }
    for (; e < e1; ++e) {
        LOADP(0); LOADV(0); ACCV(0);
    }

    uint4 o;
    o.x = (unsigned)f2b(acc[0]) | ((unsigned)f2b(acc[1]) << 16);
    o.y = (unsigned)f2b(acc[2]) | ((unsigned)f2b(acc[3]) << 16);
    o.z = (unsigned)f2b(acc[4]) | ((unsigned)f2b(acc[5]) << 16);
    o.w = (unsigned)f2b(acc[6]) | ((unsigned)f2b(acc[7]) << 16);
    *(uint4*)(outb + (size_t)node * F + lane * 8) = o;
}

extern "C" void kernel_launch(void* const* d_in, const int* in_sizes, int n_in,
                              void* d_out, int out_size, void* d_ws, size_t ws_size,
                              hipStream_t stream) {
    const float* x  = (const float*)d_in[0];
    const int*   ei = (const int*)d_in[1];
    const float* W1 = (const float*)d_in[2];
    const float* b1 = (const float*)d_in[3];
    const float* W2 = (const float*)d_in[4];
    const float* b2 = (const float*)d_in[5];
    float* out = (float*)d_out;

    char* ws = (char*)d_ws;
    size_t off = 0;
    auto alloc = [&](size_t bytes) -> void* {
        off = (off + 255) & ~(size_t)255;
        void* p = ws + off;
        off += bytes;
        return p;
    };

    unsigned short* tb  = (unsigned short*)alloc((size_t)N_NODES * F * 2); // agg out (bf16)
    unsigned short* W1t = (unsigned short*)alloc((size_t)F * F * 2);
    unsigned short* W2t = (unsigned short*)alloc((size_t)F * F * 2);
    unsigned int*   deg = (unsigned int*)alloc((size_t)N_NODES * 4);
    float*          dis = (float*)alloc((size_t)N_NODES * 4);
    int2*           seg = (int2*)alloc((size_t)N_NODES * 8);
    unsigned int*   cur = (unsigned int*)alloc((size_t)N_NODES * 4);
    unsigned int*   cnt = (unsigned int*)alloc(256);
    uint2*          ev  = (uint2*)alloc((size_t)E_TOT * 8);

    // d_out doubles as scratch: lower half = h1 (bf16), upper half = x (bf16).
    unsigned short* h1b = (unsigned short*)d_out;
    unsigned short* xb  = (unsigned short*)((char*)d_out + (size_t)N_NODES * F * 2);

    int nb = (N_NODES + 255) / 256;

    k_init<<<nb, 256, 0, stream>>>(deg, cnt);
    k_hist<<<(E_EDGES + 255) / 256, 256, 0, stream>>>(ei, deg);
    k_disalloc<<<nb, 256, 0, stream>>>(deg, cnt, dis, seg, cur);
    k_scatter<<<(E_TOT + 255) / 256, 256, 0, stream>>>(ei, dis, cur, ev);

    k_cvtW<<<(2 * F * F) / 256, 256, 0, stream>>>(W1, W2, W1t, W2t);
    k_cvtX<<<(N_NODES * F / 8) / 256, 256, 0, stream>>>(x, xb);

    dim3 ggrid(4, (N_NODES + 255) / 256);   // 4 N-tiles innermost

    // layer 1: h1 = relu((A x) W1 + b1)   [reassociated]
    k_agg<<<(N_NODES + 3) / 4, 256, 0, stream>>>(xb, seg, ev, tb);
    gemm_bt<<<ggrid, 512, 0, stream>>>(tb, W1t, b1, h1b, nullptr, 1, N_NODES);

    // layer 2: out = (A h1) W2 + b2       [reassociated]
    k_agg<<<(N_NODES + 3) / 4, 256, 0, stream>>>(h1b, seg, ev, tb);
    gemm_bt<<<ggrid, 512, 0, stream>>>(tb, W2t, b2, nullptr, out, 0, N_NODES);
}